// Round 13
// baseline (203.669 us; speedup 1.0000x reference)
//
#include <hip/hip_runtime.h>

typedef unsigned short u16;
typedef float f32x4 __attribute__((ext_vector_type(4)));
typedef short short8 __attribute__((ext_vector_type(8)));
typedef unsigned int uint2v __attribute__((ext_vector_type(2)));
typedef unsigned int uint4v __attribute__((ext_vector_type(4)));

#define STRW 72           // u16 stride for weight tiles (144B rows, 16B-aligned)
#define STRU 36           // uint stride for per-wave scratch (144B rows)
#define LENT 998
#define NSAMP 63872       // 64 * 998
#define TILE_U16 4608     // 64*STRW, one padded tile
#define LTILES_U16 27648  // 6 tiles per latent
#define WS_NEED (8 * LTILES_U16 * 2)  // 442368 B

#define LDSFENCE() asm volatile("s_waitcnt lgkmcnt(0)" ::: "memory")

static __device__ __forceinline__ unsigned int rndbf(float v) {
    return (__builtin_bit_cast(unsigned int, v) + 0x8000u) & 0xFFFF0000u;
}
static __device__ __forceinline__ void split3(float v, unsigned int& a,
                                              unsigned int& b, unsigned int& c) {
    a = rndbf(v);
    float r1 = v - __builtin_bit_cast(float, a);
    b = rndbf(r1);
    float r2 = r1 - __builtin_bit_cast(float, b);
    c = rndbf(r2);
}
static __device__ __forceinline__ unsigned int packb(unsigned int x, unsigned int y) {
    return (x >> 16) | (y & 0xFFFF0000u);
}

// ---------------------------------------------------------------------------
// Prep: split W1/W2 of latent l (blockIdx.x) into 6 bf16 tiles stored as
// exact padded LDS images in ws. Mapping replicates R12's staging verbatim.
// ---------------------------------------------------------------------------
__global__ __launch_bounds__(256) void wsplit_prep(
    const float* __restrict__ gW1p, const float* __restrict__ gW2p,
    u16* __restrict__ ws)
{
    const int l = blockIdx.x, tid = threadIdx.x;
    const int row = tid >> 2, col = (tid & 3) * 16;
    const f32x4* g1 = (const f32x4*)(gW1p + (size_t)l * 4096) + tid * 4;
    const f32x4* g2 = (const f32x4*)(gW2p + (size_t)l * 4096) + tid * 4;
    u16* base = ws + (size_t)l * LTILES_U16;
#pragma unroll
    for (int h = 0; h < 2; ++h) {
        f32x4 u0 = g1[h * 2], u1 = g1[h * 2 + 1];
        f32x4 v0 = g2[h * 2], v1 = g2[h * 2 + 1];
        unsigned int a[8], b[8], c[8], d[8], e[8], f[8];
#pragma unroll
        for (int i = 0; i < 4; ++i) {
            split3(u0[i], a[i], b[i], c[i]);
            split3(u1[i], a[4 + i], b[4 + i], c[4 + i]);
            split3(v0[i], d[i], e[i], f[i]);
            split3(v1[i], d[4 + i], e[4 + i], f[4 + i]);
        }
        uint4v pa, pb, pc, pd, pe, pf;
#pragma unroll
        for (int k = 0; k < 4; ++k) {
            pa[k] = packb(a[2 * k], a[2 * k + 1]);
            pb[k] = packb(b[2 * k], b[2 * k + 1]);
            pc[k] = packb(c[2 * k], c[2 * k + 1]);
            pd[k] = packb(d[2 * k], d[2 * k + 1]);
            pe[k] = packb(e[2 * k], e[2 * k + 1]);
            pf[k] = packb(f[2 * k], f[2 * k + 1]);
        }
        const int o = row * STRW + col + h * 8;
        *(uint4v*)&base[0 * TILE_U16 + o] = pa;
        *(uint4v*)&base[1 * TILE_U16 + o] = pb;
        *(uint4v*)&base[2 * TILE_U16 + o] = pc;
        *(uint4v*)&base[3 * TILE_U16 + o] = pd;
        *(uint4v*)&base[4 * TILE_U16 + o] = pe;
        *(uint4v*)&base[5 * TILE_U16 + o] = pf;
    }
}

// ---------------------------------------------------------------------------
// R13 main: R12's verified compute core; l-loop in-block (grid 998); weight
// tiles copied pre-split from ws (no per-block split3 staging); logdet in
// registers -> plain store (no atomics / memset).
// ---------------------------------------------------------------------------
__global__ __launch_bounds__(256, 2) void mlp_fast(
    const float* __restrict__ xp,  const float* __restrict__ embp,
    const float* __restrict__ gW0p, const float* __restrict__ gb0p,
    const float* __restrict__ gb1p, const float* __restrict__ gb2p,
    const float* __restrict__ gW3p, const float* __restrict__ gb3p,
    const u16* __restrict__ ws, float* __restrict__ out)
{
    __shared__ u16 sW[6 * TILE_U16];
    __shared__ unsigned int scrH[4][16 * STRU];
    __shared__ unsigned int scrD[4][16 * STRU];
    __shared__ float sb1[64], sb2[64], sw3[64], sw0c[64], sE0[64], semb[16];

    const int tid = threadIdx.x;
    const int wave = tid >> 6, lane = tid & 63;
    const int q = lane >> 4, s = lane & 15;
    const int t = blockIdx.x;
    const int bsmp = wave * 16 + s;
    const f32x4 zf = {0.f, 0.f, 0.f, 0.f};

    if (tid < 16) semb[tid] = embp[(t + 2) * 16 + tid];
    float ldAcc = 0.f;

    const u16* sW1a = sW;                 const u16* sW1b = sW + TILE_U16;
    const u16* sW1c = sW + 2 * TILE_U16;  const u16* sW2a = sW + 3 * TILE_U16;
    const u16* sW2b = sW + 4 * TILE_U16;  const u16* sW2c = sW + 5 * TILE_U16;

    for (int l = 0; l < 8; ++l) {
        __syncthreads();   // guard prior iteration's LDS reads
        {   // straight copy of 6 pre-split tiles (55296 B), conflict-free
            const uint4v* src = (const uint4v*)(ws + (size_t)l * LTILES_U16);
            uint4v* dst = (uint4v*)sW;
            for (int i = tid; i < 3456; i += 256) dst[i] = src[i];
        }
        if (tid < 64) {   // E0 = b0 + W0[:, :16] @ emb; w0c; small vectors
            const float* r = gW0p + (size_t)(l * 64 + tid) * 17;
            float acc = gb0p[l * 64 + tid];
#pragma unroll
            for (int e = 0; e < 16; e++) acc = fmaf(r[e], semb[e], acc);
            sE0[tid]  = acc;
            sw0c[tid] = r[16];
            sb1[tid]  = gb1p[l * 64 + tid];
            sb2[tid]  = gb2p[l * 64 + tid];
            sw3[tid]  = gW3p[l * 64 + tid];
        }
        __syncthreads();

        const float b3v = gb3p[l];
        const float xv = xp[(size_t)(bsmp * 1000 + t + 2) * 8 + l];

        // ---- layer 0 -> 3-split B-frags (R12-verified) ----
        short8 H0a[2], H0b[2], H0c[2], D0a[2], D0b[2], D0c[2];
#pragma unroll
        for (int kc = 0; kc < 2; ++kc) {
            f32x4 eA = *(const f32x4*)&sE0[kc * 32 + q * 8];
            f32x4 eB = *(const f32x4*)&sE0[kc * 32 + q * 8 + 4];
            f32x4 wA = *(const f32x4*)&sw0c[kc * 32 + q * 8];
            f32x4 wB = *(const f32x4*)&sw0c[kc * 32 + q * 8 + 4];
            unsigned int ha[8], hb[8], hc[8], da[8], db[8], dc[8];
#pragma unroll
            for (int i = 0; i < 8; ++i) {
                float w  = (i < 4) ? wA[i] : wB[i - 4];
                float e0 = (i < 4) ? eA[i] : eB[i - 4];
                float p  = fmaf(w, xv, e0);
                float hv = fmaxf(p, 0.2f * p);
                float dv = (p >= 0.f ? 1.f : 0.2f) * w;
                split3(hv, ha[i], hb[i], hc[i]);
                split3(dv, da[i], db[i], dc[i]);
            }
            uint4v A, B, C, D, E, F;
#pragma unroll
            for (int k = 0; k < 4; ++k) {
                A[k] = packb(ha[2 * k], ha[2 * k + 1]);
                B[k] = packb(hb[2 * k], hb[2 * k + 1]);
                C[k] = packb(hc[2 * k], hc[2 * k + 1]);
                D[k] = packb(da[2 * k], da[2 * k + 1]);
                E[k] = packb(db[2 * k], db[2 * k + 1]);
                F[k] = packb(dc[2 * k], dc[2 * k + 1]);
            }
            H0a[kc] = __builtin_bit_cast(short8, A);
            H0b[kc] = __builtin_bit_cast(short8, B);
            H0c[kc] = __builtin_bit_cast(short8, C);
            D0a[kc] = __builtin_bit_cast(short8, D);
            D0b[kc] = __builtin_bit_cast(short8, E);
            D0c[kc] = __builtin_bit_cast(short8, F);
        }

        // ---- layer 1: 6-term split GEMM ----
        f32x4 aV[4], aT[4];
#pragma unroll
        for (int mb = 0; mb < 4; ++mb) { aV[mb] = zf; aT[mb] = zf; }
#pragma unroll
        for (int kc = 0; kc < 2; ++kc) {
#pragma unroll
            for (int mb = 0; mb < 4; ++mb) {
                const int wo = (mb * 16 + s) * STRW + kc * 32 + q * 8;
                short8 wa = __builtin_bit_cast(short8, *(const uint4v*)&sW1a[wo]);
                short8 wb = __builtin_bit_cast(short8, *(const uint4v*)&sW1b[wo]);
                short8 wc = __builtin_bit_cast(short8, *(const uint4v*)&sW1c[wo]);
                aV[mb] = __builtin_amdgcn_mfma_f32_16x16x32_bf16(wb, H0b[kc], aV[mb], 0, 0, 0);
                aV[mb] = __builtin_amdgcn_mfma_f32_16x16x32_bf16(wc, H0a[kc], aV[mb], 0, 0, 0);
                aV[mb] = __builtin_amdgcn_mfma_f32_16x16x32_bf16(wa, H0c[kc], aV[mb], 0, 0, 0);
                aV[mb] = __builtin_amdgcn_mfma_f32_16x16x32_bf16(wb, H0a[kc], aV[mb], 0, 0, 0);
                aV[mb] = __builtin_amdgcn_mfma_f32_16x16x32_bf16(wa, H0b[kc], aV[mb], 0, 0, 0);
                aV[mb] = __builtin_amdgcn_mfma_f32_16x16x32_bf16(wa, H0a[kc], aV[mb], 0, 0, 0);
                aT[mb] = __builtin_amdgcn_mfma_f32_16x16x32_bf16(wb, D0b[kc], aT[mb], 0, 0, 0);
                aT[mb] = __builtin_amdgcn_mfma_f32_16x16x32_bf16(wc, D0a[kc], aT[mb], 0, 0, 0);
                aT[mb] = __builtin_amdgcn_mfma_f32_16x16x32_bf16(wa, D0c[kc], aT[mb], 0, 0, 0);
                aT[mb] = __builtin_amdgcn_mfma_f32_16x16x32_bf16(wb, D0a[kc], aT[mb], 0, 0, 0);
                aT[mb] = __builtin_amdgcn_mfma_f32_16x16x32_bf16(wa, D0b[kc], aT[mb], 0, 0, 0);
                aT[mb] = __builtin_amdgcn_mfma_f32_16x16x32_bf16(wa, D0a[kc], aT[mb], 0, 0, 0);
            }
        }

        // ---- activation + 3-pass C->B transform (per-wave scratch) ----
        uint2v hp1[4], hp2[4], hp3[4], dp1[4], dp2[4], dp3[4];
#pragma unroll
        for (int mb = 0; mb < 4; ++mb) {
            f32x4 b1v = *(const f32x4*)&sb1[mb * 16 + q * 4];
            unsigned int ha[4], hb[4], hc[4], da[4], db[4], dc[4];
#pragma unroll
            for (int i = 0; i < 4; ++i) {
                float p  = aV[mb][i] + b1v[i];
                float hv = fmaxf(p, 0.2f * p);
                float dv = (p >= 0.f ? 1.f : 0.2f) * aT[mb][i];
                split3(hv, ha[i], hb[i], hc[i]);
                split3(dv, da[i], db[i], dc[i]);
            }
            hp1[mb][0] = packb(ha[0], ha[1]); hp1[mb][1] = packb(ha[2], ha[3]);
            hp2[mb][0] = packb(hb[0], hb[1]); hp2[mb][1] = packb(hb[2], hb[3]);
            hp3[mb][0] = packb(hc[0], hc[1]); hp3[mb][1] = packb(hc[2], hc[3]);
            dp1[mb][0] = packb(da[0], da[1]); dp1[mb][1] = packb(da[2], da[3]);
            dp2[mb][0] = packb(db[0], db[1]); dp2[mb][1] = packb(db[2], db[3]);
            dp3[mb][0] = packb(dc[0], dc[1]); dp3[mb][1] = packb(dc[2], dc[3]);
        }
        unsigned int* mH = scrH[wave];
        unsigned int* mD = scrD[wave];
        short8 H1a[2], H1b[2], H1c[2], D1a[2], D1b[2], D1c[2];
#pragma unroll
        for (int mb = 0; mb < 4; ++mb) {
            *(uint2v*)&mH[s * STRU + mb * 8 + q * 2] = hp1[mb];
            *(uint2v*)&mD[s * STRU + mb * 8 + q * 2] = dp1[mb];
        }
        LDSFENCE();
#pragma unroll
        for (int kc = 0; kc < 2; ++kc) {
            H1a[kc] = __builtin_bit_cast(short8, *(const uint4v*)&mH[s * STRU + kc * 16 + q * 4]);
            D1a[kc] = __builtin_bit_cast(short8, *(const uint4v*)&mD[s * STRU + kc * 16 + q * 4]);
        }
        LDSFENCE();
#pragma unroll
        for (int mb = 0; mb < 4; ++mb) {
            *(uint2v*)&mH[s * STRU + mb * 8 + q * 2] = hp2[mb];
            *(uint2v*)&mD[s * STRU + mb * 8 + q * 2] = dp2[mb];
        }
        LDSFENCE();
#pragma unroll
        for (int kc = 0; kc < 2; ++kc) {
            H1b[kc] = __builtin_bit_cast(short8, *(const uint4v*)&mH[s * STRU + kc * 16 + q * 4]);
            D1b[kc] = __builtin_bit_cast(short8, *(const uint4v*)&mD[s * STRU + kc * 16 + q * 4]);
        }
        LDSFENCE();
#pragma unroll
        for (int mb = 0; mb < 4; ++mb) {
            *(uint2v*)&mH[s * STRU + mb * 8 + q * 2] = hp3[mb];
            *(uint2v*)&mD[s * STRU + mb * 8 + q * 2] = dp3[mb];
        }
        LDSFENCE();
#pragma unroll
        for (int kc = 0; kc < 2; ++kc) {
            H1c[kc] = __builtin_bit_cast(short8, *(const uint4v*)&mH[s * STRU + kc * 16 + q * 4]);
            D1c[kc] = __builtin_bit_cast(short8, *(const uint4v*)&mD[s * STRU + kc * 16 + q * 4]);
        }

        // ---- layer 2: 6-term split GEMM ----
#pragma unroll
        for (int mb = 0; mb < 4; ++mb) { aV[mb] = zf; aT[mb] = zf; }
#pragma unroll
        for (int kc = 0; kc < 2; ++kc) {
#pragma unroll
            for (int mb = 0; mb < 4; ++mb) {
                const int wo = (mb * 16 + s) * STRW + kc * 32 + q * 8;
                short8 wa = __builtin_bit_cast(short8, *(const uint4v*)&sW2a[wo]);
                short8 wb = __builtin_bit_cast(short8, *(const uint4v*)&sW2b[wo]);
                short8 wc = __builtin_bit_cast(short8, *(const uint4v*)&sW2c[wo]);
                aV[mb] = __builtin_amdgcn_mfma_f32_16x16x32_bf16(wb, H1b[kc], aV[mb], 0, 0, 0);
                aV[mb] = __builtin_amdgcn_mfma_f32_16x16x32_bf16(wc, H1a[kc], aV[mb], 0, 0, 0);
                aV[mb] = __builtin_amdgcn_mfma_f32_16x16x32_bf16(wa, H1c[kc], aV[mb], 0, 0, 0);
                aV[mb] = __builtin_amdgcn_mfma_f32_16x16x32_bf16(wb, H1a[kc], aV[mb], 0, 0, 0);
                aV[mb] = __builtin_amdgcn_mfma_f32_16x16x32_bf16(wa, H1b[kc], aV[mb], 0, 0, 0);
                aV[mb] = __builtin_amdgcn_mfma_f32_16x16x32_bf16(wa, H1a[kc], aV[mb], 0, 0, 0);
                aT[mb] = __builtin_amdgcn_mfma_f32_16x16x32_bf16(wb, D1b[kc], aT[mb], 0, 0, 0);
                aT[mb] = __builtin_amdgcn_mfma_f32_16x16x32_bf16(wc, D1a[kc], aT[mb], 0, 0, 0);
                aT[mb] = __builtin_amdgcn_mfma_f32_16x16x32_bf16(wa, D1c[kc], aT[mb], 0, 0, 0);
                aT[mb] = __builtin_amdgcn_mfma_f32_16x16x32_bf16(wb, D1a[kc], aT[mb], 0, 0, 0);
                aT[mb] = __builtin_amdgcn_mfma_f32_16x16x32_bf16(wa, D1b[kc], aT[mb], 0, 0, 0);
                aT[mb] = __builtin_amdgcn_mfma_f32_16x16x32_bf16(wa, D1a[kc], aT[mb], 0, 0, 0);
            }
        }

        // ---- layer 3 + butterfly + outputs ----
        float rs = 0.f, js = 0.f;
#pragma unroll
        for (int mb = 0; mb < 4; ++mb) {
            f32x4 b2v = *(const f32x4*)&sb2[mb * 16 + q * 4];
            f32x4 w3v = *(const f32x4*)&sw3[mb * 16 + q * 4];
#pragma unroll
            for (int i = 0; i < 4; ++i) {
                float p = aV[mb][i] + b2v[i];
                float h = fmaxf(p, 0.2f * p);
                float d = (p >= 0.f ? 1.f : 0.2f) * aT[mb][i];
                rs = fmaf(w3v[i], h, rs);
                js = fmaf(w3v[i], d, js);
            }
        }
        rs += __shfl_xor(rs, 16, 64); rs += __shfl_xor(rs, 32, 64);
        js += __shfl_xor(js, 16, 64); js += __shfl_xor(js, 32, 64);
        if (lane < 16)
            out[(size_t)(bsmp * LENT + t) * 8 + l] = rs + b3v;
        ldAcc += __logf(fabsf(js));
    }

    if (lane < 16)
        out[(size_t)NSAMP * 8 + (size_t)bsmp * LENT + t] = ldAcc;
}

// ---------------------------------------------------------------------------
// Fallback: R12 kernel verbatim (per-block staging + atomics), used only if
// ws_size is too small for the pre-split tiles.
// ---------------------------------------------------------------------------
__global__ __launch_bounds__(256, 2) void mlp_split3(
    const float* __restrict__ xp,  const float* __restrict__ embp,
    const float* __restrict__ gW0p, const float* __restrict__ gb0p,
    const float* __restrict__ gW1p, const float* __restrict__ gb1p,
    const float* __restrict__ gW2p, const float* __restrict__ gb2p,
    const float* __restrict__ gW3p, const float* __restrict__ gb3p,
    float* __restrict__ out)
{
    __shared__ u16 sW1a[64 * STRW], sW1b[64 * STRW], sW1c[64 * STRW];
    __shared__ u16 sW2a[64 * STRW], sW2b[64 * STRW], sW2c[64 * STRW];
    __shared__ unsigned int scrH[4][16 * STRU];
    __shared__ unsigned int scrD[4][16 * STRU];
    __shared__ float sb1[64], sb2[64], sw3[64], sw0c[64], sE0[64], semb[16];

    const int tid = threadIdx.x;
    const int wave = tid >> 6, lane = tid & 63;
    const int q = lane >> 4, s = lane & 15;
    const int t = blockIdx.x, l = blockIdx.y;

    if (tid < 16) semb[tid] = embp[(t + 2) * 16 + tid];
    __syncthreads();

    {
        const int row = tid >> 2, col = (tid & 3) * 16;
        const f32x4* g1 = (const f32x4*)(gW1p + (size_t)l * 4096) + tid * 4;
        const f32x4* g2 = (const f32x4*)(gW2p + (size_t)l * 4096) + tid * 4;
#pragma unroll
        for (int h = 0; h < 2; ++h) {
            f32x4 u0 = g1[h * 2], u1 = g1[h * 2 + 1];
            f32x4 v0 = g2[h * 2], v1 = g2[h * 2 + 1];
            unsigned int a[8], b[8], c[8], d[8], e[8], f[8];
#pragma unroll
            for (int i = 0; i < 4; ++i) {
                split3(u0[i], a[i], b[i], c[i]);
                split3(u1[i], a[4 + i], b[4 + i], c[4 + i]);
                split3(v0[i], d[i], e[i], f[i]);
                split3(v1[i], d[4 + i], e[4 + i], f[4 + i]);
            }
            uint4v pa, pb, pc, pd, pe, pf;
#pragma unroll
            for (int k = 0; k < 4; ++k) {
                pa[k] = packb(a[2 * k], a[2 * k + 1]);
                pb[k] = packb(b[2 * k], b[2 * k + 1]);
                pc[k] = packb(c[2 * k], c[2 * k + 1]);
                pd[k] = packb(d[2 * k], d[2 * k + 1]);
                pe[k] = packb(e[2 * k], e[2 * k + 1]);
                pf[k] = packb(f[2 * k], f[2 * k + 1]);
            }
            *(uint4v*)&sW1a[row * STRW + col + h * 8] = pa;
            *(uint4v*)&sW1b[row * STRW + col + h * 8] = pb;
            *(uint4v*)&sW1c[row * STRW + col + h * 8] = pc;
            *(uint4v*)&sW2a[row * STRW + col + h * 8] = pd;
            *(uint4v*)&sW2b[row * STRW + col + h * 8] = pe;
            *(uint4v*)&sW2c[row * STRW + col + h * 8] = pf;
        }
    }
    if (tid < 64) {
        const float* r = gW0p + (size_t)(l * 64 + tid) * 17;
        float acc = gb0p[l * 64 + tid];
#pragma unroll
        for (int e = 0; e < 16; e++) acc = fmaf(r[e], semb[e], acc);
        sE0[tid]  = acc;
        sw0c[tid] = r[16];
        sb1[tid]  = gb1p[l * 64 + tid];
        sb2[tid]  = gb2p[l * 64 + tid];
        sw3[tid]  = gW3p[l * 64 + tid];
    }
    __syncthreads();

    const float b3v = gb3p[l];
    const int bsmp = wave * 16 + s;
    const float xv = xp[(size_t)(bsmp * 1000 + t + 2) * 8 + l];
    const f32x4 zf = {0.f, 0.f, 0.f, 0.f};

    short8 H0a[2], H0b[2], H0c[2], D0a[2], D0b[2], D0c[2];
#pragma unroll
    for (int kc = 0; kc < 2; ++kc) {
        f32x4 eA = *(const f32x4*)&sE0[kc * 32 + q * 8];
        f32x4 eB = *(const f32x4*)&sE0[kc * 32 + q * 8 + 4];
        f32x4 wA = *(const f32x4*)&sw0c[kc * 32 + q * 8];
        f32x4 wB = *(const f32x4*)&sw0c[kc * 32 + q * 8 + 4];
        unsigned int ha[8], hb[8], hc[8], da[8], db[8], dc[8];
#pragma unroll
        for (int i = 0; i < 8; ++i) {
            float w  = (i < 4) ? wA[i] : wB[i - 4];
            float e0 = (i < 4) ? eA[i] : eB[i - 4];
            float p  = fmaf(w, xv, e0);
            float hv = fmaxf(p, 0.2f * p);
            float dv = (p >= 0.f ? 1.f : 0.2f) * w;
            split3(hv, ha[i], hb[i], hc[i]);
            split3(dv, da[i], db[i], dc[i]);
        }
        uint4v A, B, C, D, E, F;
#pragma unroll
        for (int k = 0; k < 4; ++k) {
            A[k] = packb(ha[2 * k], ha[2 * k + 1]);
            B[k] = packb(hb[2 * k], hb[2 * k + 1]);
            C[k] = packb(hc[2 * k], hc[2 * k + 1]);
            D[k] = packb(da[2 * k], da[2 * k + 1]);
            E[k] = packb(db[2 * k], db[2 * k + 1]);
            F[k] = packb(dc[2 * k], dc[2 * k + 1]);
        }
        H0a[kc] = __builtin_bit_cast(short8, A);
        H0b[kc] = __builtin_bit_cast(short8, B);
        H0c[kc] = __builtin_bit_cast(short8, C);
        D0a[kc] = __builtin_bit_cast(short8, D);
        D0b[kc] = __builtin_bit_cast(short8, E);
        D0c[kc] = __builtin_bit_cast(short8, F);
    }

    f32x4 aV[4], aT[4];
#pragma unroll
    for (int mb = 0; mb < 4; ++mb) { aV[mb] = zf; aT[mb] = zf; }
#pragma unroll
    for (int kc = 0; kc < 2; ++kc) {
#pragma unroll
        for (int mb = 0; mb < 4; ++mb) {
            const int wo = (mb * 16 + s) * STRW + kc * 32 + q * 8;
            short8 wa = __builtin_bit_cast(short8, *(const uint4v*)&sW1a[wo]);
            short8 wb = __builtin_bit_cast(short8, *(const uint4v*)&sW1b[wo]);
            short8 wc = __builtin_bit_cast(short8, *(const uint4v*)&sW1c[wo]);
            aV[mb] = __builtin_amdgcn_mfma_f32_16x16x32_bf16(wb, H0b[kc], aV[mb], 0, 0, 0);
            aV[mb] = __builtin_amdgcn_mfma_f32_16x16x32_bf16(wc, H0a[kc], aV[mb], 0, 0, 0);
            aV[mb] = __builtin_amdgcn_mfma_f32_16x16x32_bf16(wa, H0c[kc], aV[mb], 0, 0, 0);
            aV[mb] = __builtin_amdgcn_mfma_f32_16x16x32_bf16(wb, H0a[kc], aV[mb], 0, 0, 0);
            aV[mb] = __builtin_amdgcn_mfma_f32_16x16x32_bf16(wa, H0b[kc], aV[mb], 0, 0, 0);
            aV[mb] = __builtin_amdgcn_mfma_f32_16x16x32_bf16(wa, H0a[kc], aV[mb], 0, 0, 0);
            aT[mb] = __builtin_amdgcn_mfma_f32_16x16x32_bf16(wb, D0b[kc], aT[mb], 0, 0, 0);
            aT[mb] = __builtin_amdgcn_mfma_f32_16x16x32_bf16(wc, D0a[kc], aT[mb], 0, 0, 0);
            aT[mb] = __builtin_amdgcn_mfma_f32_16x16x32_bf16(wa, D0c[kc], aT[mb], 0, 0, 0);
            aT[mb] = __builtin_amdgcn_mfma_f32_16x16x32_bf16(wb, D0a[kc], aT[mb], 0, 0, 0);
            aT[mb] = __builtin_amdgcn_mfma_f32_16x16x32_bf16(wa, D0b[kc], aT[mb], 0, 0, 0);
            aT[mb] = __builtin_amdgcn_mfma_f32_16x16x32_bf16(wa, D0a[kc], aT[mb], 0, 0, 0);
        }
    }

    uint2v hp1[4], hp2[4], hp3[4], dp1[4], dp2[4], dp3[4];
#pragma unroll
    for (int mb = 0; mb < 4; ++mb) {
        f32x4 b1v = *(const f32x4*)&sb1[mb * 16 + q * 4];
        unsigned int ha[4], hb[4], hc[4], da[4], db[4], dc[4];
#pragma unroll
        for (int i = 0; i < 4; ++i) {
            float p  = aV[mb][i] + b1v[i];
            float hv = fmaxf(p, 0.2f * p);
            float dv = (p >= 0.f ? 1.f : 0.2f) * aT[mb][i];
            split3(hv, ha[i], hb[i], hc[i]);
            split3(dv, da[i], db[i], dc[i]);
        }
        hp1[mb][0] = packb(ha[0], ha[1]); hp1[mb][1] = packb(ha[2], ha[3]);
        hp2[mb][0] = packb(hb[0], hb[1]); hp2[mb][1] = packb(hb[2], hb[3]);
        hp3[mb][0] = packb(hc[0], hc[1]); hp3[mb][1] = packb(hc[2], hc[3]);
        dp1[mb][0] = packb(da[0], da[1]); dp1[mb][1] = packb(da[2], da[3]);
        dp2[mb][0] = packb(db[0], db[1]); dp2[mb][1] = packb(db[2], db[3]);
        dp3[mb][0] = packb(dc[0], dc[1]); dp3[mb][1] = packb(dc[2], dc[3]);
    }
    unsigned int* mH = scrH[wave];
    unsigned int* mD = scrD[wave];
    short8 H1a[2], H1b[2], H1c[2], D1a[2], D1b[2], D1c[2];
#pragma unroll
    for (int mb = 0; mb < 4; ++mb) {
        *(uint2v*)&mH[s * STRU + mb * 8 + q * 2] = hp1[mb];
        *(uint2v*)&mD[s * STRU + mb * 8 + q * 2] = dp1[mb];
    }
    LDSFENCE();
#pragma unroll
    for (int kc = 0; kc < 2; ++kc) {
        H1a[kc] = __builtin_bit_cast(short8, *(const uint4v*)&mH[s * STRU + kc * 16 + q * 4]);
        D1a[kc] = __builtin_bit_cast(short8, *(const uint4v*)&mD[s * STRU + kc * 16 + q * 4]);
    }
    LDSFENCE();
#pragma unroll
    for (int mb = 0; mb < 4; ++mb) {
        *(uint2v*)&mH[s * STRU + mb * 8 + q * 2] = hp2[mb];
        *(uint2v*)&mD[s * STRU + mb * 8 + q * 2] = dp2[mb];
    }
    LDSFENCE();
#pragma unroll
    for (int kc = 0; kc < 2; ++kc) {
        H1b[kc] = __builtin_bit_cast(short8, *(const uint4v*)&mH[s * STRU + kc * 16 + q * 4]);
        D1b[kc] = __builtin_bit_cast(short8, *(const uint4v*)&mD[s * STRU + kc * 16 + q * 4]);
    }
    LDSFENCE();
#pragma unroll
    for (int mb = 0; mb < 4; ++mb) {
        *(uint2v*)&mH[s * STRU + mb * 8 + q * 2] = hp3[mb];
        *(uint2v*)&mD[s * STRU + mb * 8 + q * 2] = dp3[mb];
    }
    LDSFENCE();
#pragma unroll
    for (int kc = 0; kc < 2; ++kc) {
        H1c[kc] = __builtin_bit_cast(short8, *(const uint4v*)&mH[s * STRU + kc * 16 + q * 4]);
        D1c[kc] = __builtin_bit_cast(short8, *(const uint4v*)&mD[s * STRU + kc * 16 + q * 4]);
    }

#pragma unroll
    for (int mb = 0; mb < 4; ++mb) { aV[mb] = zf; aT[mb] = zf; }
#pragma unroll
    for (int kc = 0; kc < 2; ++kc) {
#pragma unroll
        for (int mb = 0; mb < 4; ++mb) {
            const int wo = (mb * 16 + s) * STRW + kc * 32 + q * 8;
            short8 wa = __builtin_bit_cast(short8, *(const uint4v*)&sW2a[wo]);
            short8 wb = __builtin_bit_cast(short8, *(const uint4v*)&sW2b[wo]);
            short8 wc = __builtin_bit_cast(short8, *(const uint4v*)&sW2c[wo]);
            aV[mb] = __builtin_amdgcn_mfma_f32_16x16x32_bf16(wb, H1b[kc], aV[mb], 0, 0, 0);
            aV[mb] = __builtin_amdgcn_mfma_f32_16x16x32_bf16(wc, H1a[kc], aV[mb], 0, 0, 0);
            aV[mb] = __builtin_amdgcn_mfma_f32_16x16x32_bf16(wa, H1c[kc], aV[mb], 0, 0, 0);
            aV[mb] = __builtin_amdgcn_mfma_f32_16x16x32_bf16(wb, H1a[kc], aV[mb], 0, 0, 0);
            aV[mb] = __builtin_amdgcn_mfma_f32_16x16x32_bf16(wa, H1b[kc], aV[mb], 0, 0, 0);
            aV[mb] = __builtin_amdgcn_mfma_f32_16x16x32_bf16(wa, H1a[kc], aV[mb], 0, 0, 0);
            aT[mb] = __builtin_amdgcn_mfma_f32_16x16x32_bf16(wb, D1b[kc], aT[mb], 0, 0, 0);
            aT[mb] = __builtin_amdgcn_mfma_f32_16x16x32_bf16(wc, D1a[kc], aT[mb], 0, 0, 0);
            aT[mb] = __builtin_amdgcn_mfma_f32_16x16x32_bf16(wa, D1c[kc], aT[mb], 0, 0, 0);
            aT[mb] = __builtin_amdgcn_mfma_f32_16x16x32_bf16(wb, D1a[kc], aT[mb], 0, 0, 0);
            aT[mb] = __builtin_amdgcn_mfma_f32_16x16x32_bf16(wa, D1b[kc], aT[mb], 0, 0, 0);
            aT[mb] = __builtin_amdgcn_mfma_f32_16x16x32_bf16(wa, D1a[kc], aT[mb], 0, 0, 0);
        }
    }

    float rs = 0.f, js = 0.f;
#pragma unroll
    for (int mb = 0; mb < 4; ++mb) {
        f32x4 b2v = *(const f32x4*)&sb2[mb * 16 + q * 4];
        f32x4 w3v = *(const f32x4*)&sw3[mb * 16 + q * 4];
#pragma unroll
        for (int i = 0; i < 4; ++i) {
            float p = aV[mb][i] + b2v[i];
            float h = fmaxf(p, 0.2f * p);
            float d = (p >= 0.f ? 1.f : 0.2f) * aT[mb][i];
            rs = fmaf(w3v[i], h, rs);
            js = fmaf(w3v[i], d, js);
        }
    }
    rs += __shfl_xor(rs, 16, 64); rs += __shfl_xor(rs, 32, 64);
    js += __shfl_xor(js, 16, 64); js += __shfl_xor(js, 32, 64);
    if (lane < 16) {
        out[(size_t)(bsmp * LENT + t) * 8 + l] = rs + b3v;
        atomicAdd(&out[(size_t)NSAMP * 8 + (size_t)bsmp * LENT + t], __logf(fabsf(js)));
    }
}

extern "C" void kernel_launch(void* const* d_in, const int* in_sizes, int n_in,
                              void* d_out, int out_size, void* d_ws, size_t ws_size,
                              hipStream_t stream) {
    (void)in_sizes; (void)n_in; (void)out_size;
    if (ws_size >= (size_t)WS_NEED) {
        wsplit_prep<<<dim3(8), 256, 0, stream>>>(
            (const float*)d_in[4], (const float*)d_in[6], (u16*)d_ws);
        mlp_fast<<<dim3(LENT), 256, 0, stream>>>(
            (const float*)d_in[0], (const float*)d_in[1],
            (const float*)d_in[2], (const float*)d_in[3],
            (const float*)d_in[5], (const float*)d_in[7],
            (const float*)d_in[8], (const float*)d_in[9],
            (const u16*)d_ws, (float*)d_out);
    } else {
        hipMemsetAsync((char*)d_out + (size_t)NSAMP * 8 * sizeof(float), 0,
                       (size_t)NSAMP * sizeof(float), stream);
        mlp_split3<<<dim3(LENT, 8), 256, 0, stream>>>(
            (const float*)d_in[0], (const float*)d_in[1],
            (const float*)d_in[2], (const float*)d_in[3],
            (const float*)d_in[4], (const float*)d_in[5],
            (const float*)d_in[6], (const float*)d_in[7],
            (const float*)d_in[8], (const float*)d_in[9],
            (float*)d_out);
    }
}

// Round 14
// 194.525 us; speedup vs baseline: 1.0470x; 1.0470x over previous
//
#include <hip/hip_runtime.h>

typedef unsigned short u16;
typedef float f32x4 __attribute__((ext_vector_type(4)));
typedef short short8 __attribute__((ext_vector_type(8)));
typedef unsigned int uint2v __attribute__((ext_vector_type(2)));
typedef unsigned int uint4v __attribute__((ext_vector_type(4)));

#define STRW 72           // u16 stride for weight tiles (144B rows, 16B-aligned)
#define STRU 36           // uint stride for per-wave scratch
#define LENT 998
#define NSAMP 63872       // 64 * 998
#define TILE_U16 4608     // 64*STRW

#define LDSFENCE() asm volatile("s_waitcnt lgkmcnt(0)" ::: "memory")

static __device__ __forceinline__ unsigned int rndbf(float v) {
    return (__builtin_bit_cast(unsigned int, v) + 0x8000u) & 0xFFFF0000u;
}
static __device__ __forceinline__ void split3(float v, unsigned int& a,
                                              unsigned int& b, unsigned int& c) {
    a = rndbf(v);
    float r1 = v - __builtin_bit_cast(float, a);
    b = rndbf(r1);
    float r2 = r1 - __builtin_bit_cast(float, b);
    c = rndbf(r2);
}
static __device__ __forceinline__ unsigned int packb(unsigned int x, unsigned int y) {
    return (x >> 16) | (y & 0xFFFF0000u);
}

// ---------------------------------------------------------------------------
// R14: single-dispatch, double-occupancy split3-MFMA.
// Grid 998 (one t per block), 256 thr = 4 waves x 16 samples, l-loop in-block.
// W1 tiles staged -> layer1 -> same LDS overwritten with W2 tiles -> layer2:
// 38.4 KB LDS -> 4 blocks/CU (16 waves/CU, 2x R13's 8). Logdet in registers
// (no atomics/memset/prep: R13's 2nd dispatch cost ~50 us). Compute core
// byte-identical to R12/R13 (verified passing, absmax 0.25).
// ---------------------------------------------------------------------------
__global__ __launch_bounds__(256, 4) void mlp_one(
    const float* __restrict__ xp,  const float* __restrict__ embp,
    const float* __restrict__ gW0p, const float* __restrict__ gb0p,
    const float* __restrict__ gW1p, const float* __restrict__ gb1p,
    const float* __restrict__ gW2p, const float* __restrict__ gb2p,
    const float* __restrict__ gW3p, const float* __restrict__ gb3p,
    float* __restrict__ out)
{
    __shared__ u16 sWa[TILE_U16], sWb[TILE_U16], sWc[TILE_U16];
    __shared__ unsigned int scrH[4][16 * STRU];
    __shared__ unsigned int scrD[4][16 * STRU];
    __shared__ float sb1[64], sb2[64], sw3[64], sw0c[64], sE0[64], semb[16];

    const int tid = threadIdx.x;
    const int wave = tid >> 6, lane = tid & 63;
    const int q = lane >> 4, s = lane & 15;
    const int t = blockIdx.x;
    const int bsmp = wave * 16 + s;
    const f32x4 zf = {0.f, 0.f, 0.f, 0.f};

    if (tid < 16) semb[tid] = embp[(t + 2) * 16 + tid];
    float ldAcc = 0.f;

    const int srow = tid >> 2, scol = (tid & 3) * 16;

    for (int l = 0; l < 8; ++l) {
        __syncthreads();   // B1: prior-iter tile reads done; semb visible (l=0)
        {   // ---- stage W1(l) as 3 split tiles (R12-verified mapping) ----
            const f32x4* g = (const f32x4*)(gW1p + (size_t)l * 4096) + tid * 4;
#pragma unroll
            for (int h = 0; h < 2; ++h) {
                f32x4 u0 = g[h * 2], u1 = g[h * 2 + 1];
                unsigned int a[8], b[8], c[8];
#pragma unroll
                for (int i = 0; i < 4; ++i) {
                    split3(u0[i], a[i], b[i], c[i]);
                    split3(u1[i], a[4 + i], b[4 + i], c[4 + i]);
                }
                uint4v pa, pb, pc;
#pragma unroll
                for (int k = 0; k < 4; ++k) {
                    pa[k] = packb(a[2 * k], a[2 * k + 1]);
                    pb[k] = packb(b[2 * k], b[2 * k + 1]);
                    pc[k] = packb(c[2 * k], c[2 * k + 1]);
                }
                const int o = srow * STRW + scol + h * 8;
                *(uint4v*)&sWa[o] = pa;
                *(uint4v*)&sWb[o] = pb;
                *(uint4v*)&sWc[o] = pc;
            }
        }
        if (tid < 64) {   // E0 = b0 + W0[:, :16] @ emb; w0c; small vectors
            const float* r = gW0p + (size_t)(l * 64 + tid) * 17;
            float acc = gb0p[l * 64 + tid];
#pragma unroll
            for (int e = 0; e < 16; e++) acc = fmaf(r[e], semb[e], acc);
            sE0[tid]  = acc;
            sw0c[tid] = r[16];
            sb1[tid]  = gb1p[l * 64 + tid];
            sb2[tid]  = gb2p[l * 64 + tid];
            sw3[tid]  = gW3p[l * 64 + tid];
        }
        __syncthreads();   // B2

        const float b3v = gb3p[l];
        const float xv = xp[(size_t)(bsmp * 1000 + t + 2) * 8 + l];

        // ---- layer 0 -> 3-split B-frags (R12-verified) ----
        short8 H0a[2], H0b[2], H0c[2], D0a[2], D0b[2], D0c[2];
#pragma unroll
        for (int kc = 0; kc < 2; ++kc) {
            f32x4 eA = *(const f32x4*)&sE0[kc * 32 + q * 8];
            f32x4 eB = *(const f32x4*)&sE0[kc * 32 + q * 8 + 4];
            f32x4 wA = *(const f32x4*)&sw0c[kc * 32 + q * 8];
            f32x4 wB = *(const f32x4*)&sw0c[kc * 32 + q * 8 + 4];
            unsigned int ha[8], hb[8], hc[8], da[8], db[8], dc[8];
#pragma unroll
            for (int i = 0; i < 8; ++i) {
                float w  = (i < 4) ? wA[i] : wB[i - 4];
                float e0 = (i < 4) ? eA[i] : eB[i - 4];
                float p  = fmaf(w, xv, e0);
                float hv = fmaxf(p, 0.2f * p);
                float dv = (p >= 0.f ? 1.f : 0.2f) * w;
                split3(hv, ha[i], hb[i], hc[i]);
                split3(dv, da[i], db[i], dc[i]);
            }
            uint4v A, B, C, D, E, F;
#pragma unroll
            for (int k = 0; k < 4; ++k) {
                A[k] = packb(ha[2 * k], ha[2 * k + 1]);
                B[k] = packb(hb[2 * k], hb[2 * k + 1]);
                C[k] = packb(hc[2 * k], hc[2 * k + 1]);
                D[k] = packb(da[2 * k], da[2 * k + 1]);
                E[k] = packb(db[2 * k], db[2 * k + 1]);
                F[k] = packb(dc[2 * k], dc[2 * k + 1]);
            }
            H0a[kc] = __builtin_bit_cast(short8, A);
            H0b[kc] = __builtin_bit_cast(short8, B);
            H0c[kc] = __builtin_bit_cast(short8, C);
            D0a[kc] = __builtin_bit_cast(short8, D);
            D0b[kc] = __builtin_bit_cast(short8, E);
            D0c[kc] = __builtin_bit_cast(short8, F);
        }

        // ---- layer 1: 6-term split GEMM ----
        f32x4 aV[4], aT[4];
#pragma unroll
        for (int mb = 0; mb < 4; ++mb) { aV[mb] = zf; aT[mb] = zf; }
#pragma unroll
        for (int kc = 0; kc < 2; ++kc) {
#pragma unroll
            for (int mb = 0; mb < 4; ++mb) {
                const int wo = (mb * 16 + s) * STRW + kc * 32 + q * 8;
                short8 wa = __builtin_bit_cast(short8, *(const uint4v*)&sWa[wo]);
                short8 wb = __builtin_bit_cast(short8, *(const uint4v*)&sWb[wo]);
                short8 wc = __builtin_bit_cast(short8, *(const uint4v*)&sWc[wo]);
                aV[mb] = __builtin_amdgcn_mfma_f32_16x16x32_bf16(wb, H0b[kc], aV[mb], 0, 0, 0);
                aV[mb] = __builtin_amdgcn_mfma_f32_16x16x32_bf16(wc, H0a[kc], aV[mb], 0, 0, 0);
                aV[mb] = __builtin_amdgcn_mfma_f32_16x16x32_bf16(wa, H0c[kc], aV[mb], 0, 0, 0);
                aV[mb] = __builtin_amdgcn_mfma_f32_16x16x32_bf16(wb, H0a[kc], aV[mb], 0, 0, 0);
                aV[mb] = __builtin_amdgcn_mfma_f32_16x16x32_bf16(wa, H0b[kc], aV[mb], 0, 0, 0);
                aV[mb] = __builtin_amdgcn_mfma_f32_16x16x32_bf16(wa, H0a[kc], aV[mb], 0, 0, 0);
                aT[mb] = __builtin_amdgcn_mfma_f32_16x16x32_bf16(wb, D0b[kc], aT[mb], 0, 0, 0);
                aT[mb] = __builtin_amdgcn_mfma_f32_16x16x32_bf16(wc, D0a[kc], aT[mb], 0, 0, 0);
                aT[mb] = __builtin_amdgcn_mfma_f32_16x16x32_bf16(wa, D0c[kc], aT[mb], 0, 0, 0);
                aT[mb] = __builtin_amdgcn_mfma_f32_16x16x32_bf16(wb, D0a[kc], aT[mb], 0, 0, 0);
                aT[mb] = __builtin_amdgcn_mfma_f32_16x16x32_bf16(wa, D0b[kc], aT[mb], 0, 0, 0);
                aT[mb] = __builtin_amdgcn_mfma_f32_16x16x32_bf16(wa, D0a[kc], aT[mb], 0, 0, 0);
            }
        }

        // ---- activation + 3-pass C->B transform (per-wave scratch) ----
        uint2v hp1[4], hp2[4], hp3[4], dp1[4], dp2[4], dp3[4];
#pragma unroll
        for (int mb = 0; mb < 4; ++mb) {
            f32x4 b1v = *(const f32x4*)&sb1[mb * 16 + q * 4];
            unsigned int ha[4], hb[4], hc[4], da[4], db[4], dc[4];
#pragma unroll
            for (int i = 0; i < 4; ++i) {
                float p  = aV[mb][i] + b1v[i];
                float hv = fmaxf(p, 0.2f * p);
                float dv = (p >= 0.f ? 1.f : 0.2f) * aT[mb][i];
                split3(hv, ha[i], hb[i], hc[i]);
                split3(dv, da[i], db[i], dc[i]);
            }
            hp1[mb][0] = packb(ha[0], ha[1]); hp1[mb][1] = packb(ha[2], ha[3]);
            hp2[mb][0] = packb(hb[0], hb[1]); hp2[mb][1] = packb(hb[2], hb[3]);
            hp3[mb][0] = packb(hc[0], hc[1]); hp3[mb][1] = packb(hc[2], hc[3]);
            dp1[mb][0] = packb(da[0], da[1]); dp1[mb][1] = packb(da[2], da[3]);
            dp2[mb][0] = packb(db[0], db[1]); dp2[mb][1] = packb(db[2], db[3]);
            dp3[mb][0] = packb(dc[0], dc[1]); dp3[mb][1] = packb(dc[2], dc[3]);
        }
        unsigned int* mH = scrH[wave];
        unsigned int* mD = scrD[wave];
        short8 H1a[2], H1b[2], H1c[2], D1a[2], D1b[2], D1c[2];
#pragma unroll
        for (int mb = 0; mb < 4; ++mb) {
            *(uint2v*)&mH[s * STRU + mb * 8 + q * 2] = hp1[mb];
            *(uint2v*)&mD[s * STRU + mb * 8 + q * 2] = dp1[mb];
        }
        LDSFENCE();
#pragma unroll
        for (int kc = 0; kc < 2; ++kc) {
            H1a[kc] = __builtin_bit_cast(short8, *(const uint4v*)&mH[s * STRU + kc * 16 + q * 4]);
            D1a[kc] = __builtin_bit_cast(short8, *(const uint4v*)&mD[s * STRU + kc * 16 + q * 4]);
        }
        LDSFENCE();
#pragma unroll
        for (int mb = 0; mb < 4; ++mb) {
            *(uint2v*)&mH[s * STRU + mb * 8 + q * 2] = hp2[mb];
            *(uint2v*)&mD[s * STRU + mb * 8 + q * 2] = dp2[mb];
        }
        LDSFENCE();
#pragma unroll
        for (int kc = 0; kc < 2; ++kc) {
            H1b[kc] = __builtin_bit_cast(short8, *(const uint4v*)&mH[s * STRU + kc * 16 + q * 4]);
            D1b[kc] = __builtin_bit_cast(short8, *(const uint4v*)&mD[s * STRU + kc * 16 + q * 4]);
        }
        LDSFENCE();
#pragma unroll
        for (int mb = 0; mb < 4; ++mb) {
            *(uint2v*)&mH[s * STRU + mb * 8 + q * 2] = hp3[mb];
            *(uint2v*)&mD[s * STRU + mb * 8 + q * 2] = dp3[mb];
        }
        LDSFENCE();
#pragma unroll
        for (int kc = 0; kc < 2; ++kc) {
            H1c[kc] = __builtin_bit_cast(short8, *(const uint4v*)&mH[s * STRU + kc * 16 + q * 4]);
            D1c[kc] = __builtin_bit_cast(short8, *(const uint4v*)&mD[s * STRU + kc * 16 + q * 4]);
        }

        __syncthreads();   // B3: all waves done reading W1 tiles
        {   // ---- stage W2(l) into the same tiles ----
            const f32x4* g = (const f32x4*)(gW2p + (size_t)l * 4096) + tid * 4;
#pragma unroll
            for (int h = 0; h < 2; ++h) {
                f32x4 u0 = g[h * 2], u1 = g[h * 2 + 1];
                unsigned int a[8], b[8], c[8];
#pragma unroll
                for (int i = 0; i < 4; ++i) {
                    split3(u0[i], a[i], b[i], c[i]);
                    split3(u1[i], a[4 + i], b[4 + i], c[4 + i]);
                }
                uint4v pa, pb, pc;
#pragma unroll
                for (int k = 0; k < 4; ++k) {
                    pa[k] = packb(a[2 * k], a[2 * k + 1]);
                    pb[k] = packb(b[2 * k], b[2 * k + 1]);
                    pc[k] = packb(c[2 * k], c[2 * k + 1]);
                }
                const int o = srow * STRW + scol + h * 8;
                *(uint4v*)&sWa[o] = pa;
                *(uint4v*)&sWb[o] = pb;
                *(uint4v*)&sWc[o] = pc;
            }
        }
        __syncthreads();   // B4

        // ---- layer 2: 6-term split GEMM ----
#pragma unroll
        for (int mb = 0; mb < 4; ++mb) { aV[mb] = zf; aT[mb] = zf; }
#pragma unroll
        for (int kc = 0; kc < 2; ++kc) {
#pragma unroll
            for (int mb = 0; mb < 4; ++mb) {
                const int wo = (mb * 16 + s) * STRW + kc * 32 + q * 8;
                short8 wa = __builtin_bit_cast(short8, *(const uint4v*)&sWa[wo]);
                short8 wb = __builtin_bit_cast(short8, *(const uint4v*)&sWb[wo]);
                short8 wc = __builtin_bit_cast(short8, *(const uint4v*)&sWc[wo]);
                aV[mb] = __builtin_amdgcn_mfma_f32_16x16x32_bf16(wb, H1b[kc], aV[mb], 0, 0, 0);
                aV[mb] = __builtin_amdgcn_mfma_f32_16x16x32_bf16(wc, H1a[kc], aV[mb], 0, 0, 0);
                aV[mb] = __builtin_amdgcn_mfma_f32_16x16x32_bf16(wa, H1c[kc], aV[mb], 0, 0, 0);
                aV[mb] = __builtin_amdgcn_mfma_f32_16x16x32_bf16(wb, H1a[kc], aV[mb], 0, 0, 0);
                aV[mb] = __builtin_amdgcn_mfma_f32_16x16x32_bf16(wa, H1b[kc], aV[mb], 0, 0, 0);
                aV[mb] = __builtin_amdgcn_mfma_f32_16x16x32_bf16(wa, H1a[kc], aV[mb], 0, 0, 0);
                aT[mb] = __builtin_amdgcn_mfma_f32_16x16x32_bf16(wb, D1b[kc], aT[mb], 0, 0, 0);
                aT[mb] = __builtin_amdgcn_mfma_f32_16x16x32_bf16(wc, D1a[kc], aT[mb], 0, 0, 0);
                aT[mb] = __builtin_amdgcn_mfma_f32_16x16x32_bf16(wa, D1c[kc], aT[mb], 0, 0, 0);
                aT[mb] = __builtin_amdgcn_mfma_f32_16x16x32_bf16(wb, D1a[kc], aT[mb], 0, 0, 0);
                aT[mb] = __builtin_amdgcn_mfma_f32_16x16x32_bf16(wa, D1b[kc], aT[mb], 0, 0, 0);
                aT[mb] = __builtin_amdgcn_mfma_f32_16x16x32_bf16(wa, D1a[kc], aT[mb], 0, 0, 0);
            }
        }

        // ---- layer 3 + butterfly + outputs ----
        float rs = 0.f, js = 0.f;
#pragma unroll
        for (int mb = 0; mb < 4; ++mb) {
            f32x4 b2v = *(const f32x4*)&sb2[mb * 16 + q * 4];
            f32x4 w3v = *(const f32x4*)&sw3[mb * 16 + q * 4];
#pragma unroll
            for (int i = 0; i < 4; ++i) {
                float p = aV[mb][i] + b2v[i];
                float h = fmaxf(p, 0.2f * p);
                float d = (p >= 0.f ? 1.f : 0.2f) * aT[mb][i];
                rs = fmaf(w3v[i], h, rs);
                js = fmaf(w3v[i], d, js);
            }
        }
        rs += __shfl_xor(rs, 16, 64); rs += __shfl_xor(rs, 32, 64);
        js += __shfl_xor(js, 16, 64); js += __shfl_xor(js, 32, 64);
        if (lane < 16)
            out[(size_t)(bsmp * LENT + t) * 8 + l] = rs + b3v;
        ldAcc += __logf(fabsf(js));
    }

    if (lane < 16)
        out[(size_t)NSAMP * 8 + (size_t)bsmp * LENT + t] = ldAcc;
}

extern "C" void kernel_launch(void* const* d_in, const int* in_sizes, int n_in,
                              void* d_out, int out_size, void* d_ws, size_t ws_size,
                              hipStream_t stream) {
    (void)in_sizes; (void)n_in; (void)out_size; (void)d_ws; (void)ws_size;
    mlp_one<<<dim3(LENT), 256, 0, stream>>>(
        (const float*)d_in[0], (const float*)d_in[1],
        (const float*)d_in[2], (const float*)d_in[3],
        (const float*)d_in[4], (const float*)d_in[5],
        (const float*)d_in[6], (const float*)d_in[7],
        (const float*)d_in[8], (const float*)d_in[9],
        (float*)d_out);
}

// Round 16
// 141.504 us; speedup vs baseline: 1.4393x; 1.3747x over previous
//
#include <hip/hip_runtime.h>

typedef unsigned short u16;
typedef float f32x4 __attribute__((ext_vector_type(4)));
typedef __fp16 f16x2 __attribute__((ext_vector_type(2)));
typedef __fp16 half8 __attribute__((ext_vector_type(8)));
typedef unsigned int uint2v __attribute__((ext_vector_type(2)));
typedef unsigned int uint4v __attribute__((ext_vector_type(4)));

#define STRW 72           // u16 stride for weight tiles (144B rows, 16B-aligned)
#define STRU 36           // uint stride for per-wave scratch
#define LENT 998
#define NSAMP 63872       // 64 * 998
#define TILE_U16 4608     // 64*STRW
#define INVS 4.8828125e-4f  // 2^-11, exact

#define LDSFENCE() asm volatile("s_waitcnt lgkmcnt(0)" ::: "memory")

// fp16 2-term split of a pair, lo PRE-SCALED by 2^11 (keeps lo in the normal
// fp16 range regardless of |v| -> immune to denorm flush; (v-hi) and *2048
// are exact fp32 ops). r[0] = packed hi pair, r[1] = packed lo*2048 pair.
// v = hi + lo'*2^-11 with error <= 2^-22 |v|.
static __device__ __forceinline__ uint2v split2s(float x, float y) {
    f16x2 h = __builtin_amdgcn_cvt_pkrtz(x, y);
    f16x2 l = __builtin_amdgcn_cvt_pkrtz((x - (float)h[0]) * 2048.f,
                                         (y - (float)h[1]) * 2048.f);
    uint2v r;
    r[0] = __builtin_bit_cast(unsigned int, h);
    r[1] = __builtin_bit_cast(unsigned int, l);
    return r;
}
static __device__ __forceinline__ void split8s(f32x4 A, f32x4 B,
                                               uint4v* hi, uint4v* lo) {
    uint2v r0 = split2s(A[0], A[1]);
    uint2v r1 = split2s(A[2], A[3]);
    uint2v r2 = split2s(B[0], B[1]);
    uint2v r3 = split2s(B[2], B[3]);
    uint4v h, l;
    h[0] = r0[0]; l[0] = r0[1];
    h[1] = r1[0]; l[1] = r1[1];
    h[2] = r2[0]; l[2] = r2[1];
    h[3] = r3[0]; l[3] = r3[1];
    *hi = h; *lo = l;
}

// ---------------------------------------------------------------------------
// R16: fp16 2-term split MFMA with scaled-lo dual accumulators.
// Per GEMM: aA += Wa@Ha; aX += Wa@Hb' + Wb'@Ha (primes = lo*2^11);
// result = aA + aX*2^-11. 3 MFMAs/GEMM (vs R14's 6), 2 weight tiles (vs 3),
// 2 transform passes (vs 3); LDS ~38.5 KB -> 4 blocks/CU (vs R14's 3).
// eps ~2^-22 unconditionally (R12's passing bf16-3term was ~1.8e-7).
// Skeleton/indexing byte-identical to R12/R14 (verified, absmax 0.25).
// Single dispatch, grid 998, l-loop in-block, logdet in registers.
// ---------------------------------------------------------------------------
__global__ __launch_bounds__(256, 4) void mlp_h2(
    const float* __restrict__ xp,  const float* __restrict__ embp,
    const float* __restrict__ gW0p, const float* __restrict__ gb0p,
    const float* __restrict__ gW1p, const float* __restrict__ gb1p,
    const float* __restrict__ gW2p, const float* __restrict__ gb2p,
    const float* __restrict__ gW3p, const float* __restrict__ gb3p,
    float* __restrict__ out)
{
    __shared__ u16 sWa[TILE_U16], sWb[TILE_U16];
    __shared__ unsigned int scrH[4][16 * STRU];
    __shared__ unsigned int scrD[4][16 * STRU];
    __shared__ float sb1[64], sb2[64], sw3[64], sw0c[64], sE0[64], semb[16];

    const int tid = threadIdx.x;
    const int wave = tid >> 6, lane = tid & 63;
    const int q = lane >> 4, s = lane & 15;
    const int t = blockIdx.x;
    const int bsmp = wave * 16 + s;
    const f32x4 zf = {0.f, 0.f, 0.f, 0.f};

    if (tid < 16) semb[tid] = embp[(t + 2) * 16 + tid];
    float ldAcc = 0.f;

    const int srow = tid >> 2, scol = (tid & 3) * 16;

    for (int l = 0; l < 8; ++l) {
        __syncthreads();   // B1: prior-iter tile reads done; semb visible (l=0)
        {   // ---- stage W1(l) as hi / scaled-lo fp16 tiles ----
            const f32x4* g = (const f32x4*)(gW1p + (size_t)l * 4096) + tid * 4;
#pragma unroll
            for (int h = 0; h < 2; ++h) {
                uint4v hi, lo;
                split8s(g[h * 2], g[h * 2 + 1], &hi, &lo);
                const int o = srow * STRW + scol + h * 8;
                *(uint4v*)&sWa[o] = hi;
                *(uint4v*)&sWb[o] = lo;
            }
        }
        if (tid < 64) {   // E0 = b0 + W0[:, :16] @ emb; w0c; small vectors
            const float* r = gW0p + (size_t)(l * 64 + tid) * 17;
            float acc = gb0p[l * 64 + tid];
#pragma unroll
            for (int e = 0; e < 16; e++) acc = fmaf(r[e], semb[e], acc);
            sE0[tid]  = acc;
            sw0c[tid] = r[16];
            sb1[tid]  = gb1p[l * 64 + tid];
            sb2[tid]  = gb2p[l * 64 + tid];
            sw3[tid]  = gW3p[l * 64 + tid];
        }
        __syncthreads();   // B2

        const float b3v = gb3p[l];
        const float xv = xp[(size_t)(bsmp * 1000 + t + 2) * 8 + l];

        // ---- layer 0 -> hi/scaled-lo fp16 B-frags (R12-verified indexing) ----
        half8 H0a[2], H0b[2], D0a[2], D0b[2];
#pragma unroll
        for (int kc = 0; kc < 2; ++kc) {
            f32x4 eA = *(const f32x4*)&sE0[kc * 32 + q * 8];
            f32x4 eB = *(const f32x4*)&sE0[kc * 32 + q * 8 + 4];
            f32x4 wA = *(const f32x4*)&sw0c[kc * 32 + q * 8];
            f32x4 wB = *(const f32x4*)&sw0c[kc * 32 + q * 8 + 4];
            float hv[8], dv[8];
#pragma unroll
            for (int i = 0; i < 8; ++i) {
                float w  = (i < 4) ? wA[i] : wB[i - 4];
                float e0 = (i < 4) ? eA[i] : eB[i - 4];
                float p  = fmaf(w, xv, e0);
                hv[i] = fmaxf(p, 0.2f * p);
                dv[i] = (p >= 0.f ? 1.f : 0.2f) * w;
            }
            uint4v Ha, Hb, Da, Db;
#pragma unroll
            for (int d2 = 0; d2 < 4; ++d2) {
                uint2v rh = split2s(hv[2 * d2], hv[2 * d2 + 1]);
                uint2v rd = split2s(dv[2 * d2], dv[2 * d2 + 1]);
                Ha[d2] = rh[0]; Hb[d2] = rh[1];
                Da[d2] = rd[0]; Db[d2] = rd[1];
            }
            H0a[kc] = __builtin_bit_cast(half8, Ha);
            H0b[kc] = __builtin_bit_cast(half8, Hb);
            D0a[kc] = __builtin_bit_cast(half8, Da);
            D0b[kc] = __builtin_bit_cast(half8, Db);
        }

        // ---- layer 1: 3-MFMA split GEMM, dual accumulators ----
        f32x4 aA[4], aX[4], tA[4], tX[4];
#pragma unroll
        for (int mb = 0; mb < 4; ++mb) { aA[mb] = zf; aX[mb] = zf; tA[mb] = zf; tX[mb] = zf; }
#pragma unroll
        for (int kc = 0; kc < 2; ++kc) {
#pragma unroll
            for (int mb = 0; mb < 4; ++mb) {
                const int wo = (mb * 16 + s) * STRW + kc * 32 + q * 8;
                half8 wa = __builtin_bit_cast(half8, *(const uint4v*)&sWa[wo]);
                half8 wb = __builtin_bit_cast(half8, *(const uint4v*)&sWb[wo]);
                aA[mb] = __builtin_amdgcn_mfma_f32_16x16x32_f16(wa, H0a[kc], aA[mb], 0, 0, 0);
                aX[mb] = __builtin_amdgcn_mfma_f32_16x16x32_f16(wa, H0b[kc], aX[mb], 0, 0, 0);
                aX[mb] = __builtin_amdgcn_mfma_f32_16x16x32_f16(wb, H0a[kc], aX[mb], 0, 0, 0);
                tA[mb] = __builtin_amdgcn_mfma_f32_16x16x32_f16(wa, D0a[kc], tA[mb], 0, 0, 0);
                tX[mb] = __builtin_amdgcn_mfma_f32_16x16x32_f16(wa, D0b[kc], tX[mb], 0, 0, 0);
                tX[mb] = __builtin_amdgcn_mfma_f32_16x16x32_f16(wb, D0a[kc], tX[mb], 0, 0, 0);
            }
        }

        // ---- activation + 2-pass hi/lo C->B transform (per-wave scratch) ----
        uint2v hpH[4], hpL[4], dpH[4], dpL[4];
#pragma unroll
        for (int mb = 0; mb < 4; ++mb) {
            f32x4 b1v = *(const f32x4*)&sb1[mb * 16 + q * 4];
            float hv[4], dv[4];
#pragma unroll
            for (int i = 0; i < 4; ++i) {
                float p  = fmaf(aX[mb][i], INVS, aA[mb][i]) + b1v[i];
                float dt = fmaf(tX[mb][i], INVS, tA[mb][i]);
                hv[i] = fmaxf(p, 0.2f * p);
                dv[i] = (p >= 0.f ? 1.f : 0.2f) * dt;
            }
            uint2v r0 = split2s(hv[0], hv[1]);
            uint2v r1 = split2s(hv[2], hv[3]);
            uint2v r2 = split2s(dv[0], dv[1]);
            uint2v r3 = split2s(dv[2], dv[3]);
            hpH[mb][0] = r0[0]; hpL[mb][0] = r0[1];
            hpH[mb][1] = r1[0]; hpL[mb][1] = r1[1];
            dpH[mb][0] = r2[0]; dpL[mb][0] = r2[1];
            dpH[mb][1] = r3[0]; dpL[mb][1] = r3[1];
        }
        unsigned int* mH = scrH[wave];
        unsigned int* mD = scrD[wave];
        half8 H1a[2], H1b[2], D1a[2], D1b[2];
        // pass 1 (hi)
#pragma unroll
        for (int mb = 0; mb < 4; ++mb) {
            *(uint2v*)&mH[s * STRU + mb * 8 + q * 2] = hpH[mb];
            *(uint2v*)&mD[s * STRU + mb * 8 + q * 2] = dpH[mb];
        }
        LDSFENCE();
#pragma unroll
        for (int kc = 0; kc < 2; ++kc) {
            H1a[kc] = __builtin_bit_cast(half8, *(const uint4v*)&mH[s * STRU + kc * 16 + q * 4]);
            D1a[kc] = __builtin_bit_cast(half8, *(const uint4v*)&mD[s * STRU + kc * 16 + q * 4]);
        }
        LDSFENCE();
        // pass 2 (scaled lo)
#pragma unroll
        for (int mb = 0; mb < 4; ++mb) {
            *(uint2v*)&mH[s * STRU + mb * 8 + q * 2] = hpL[mb];
            *(uint2v*)&mD[s * STRU + mb * 8 + q * 2] = dpL[mb];
        }
        LDSFENCE();
#pragma unroll
        for (int kc = 0; kc < 2; ++kc) {
            H1b[kc] = __builtin_bit_cast(half8, *(const uint4v*)&mH[s * STRU + kc * 16 + q * 4]);
            D1b[kc] = __builtin_bit_cast(half8, *(const uint4v*)&mD[s * STRU + kc * 16 + q * 4]);
        }

        __syncthreads();   // B3: all waves done reading W1 tiles
        {   // ---- stage W2(l) into the same tiles ----
            const f32x4* g = (const f32x4*)(gW2p + (size_t)l * 4096) + tid * 4;
#pragma unroll
            for (int h = 0; h < 2; ++h) {
                uint4v hi, lo;
                split8s(g[h * 2], g[h * 2 + 1], &hi, &lo);
                const int o = srow * STRW + scol + h * 8;
                *(uint4v*)&sWa[o] = hi;
                *(uint4v*)&sWb[o] = lo;
            }
        }
        __syncthreads();   // B4

        // ---- layer 2: 3-MFMA split GEMM, dual accumulators ----
#pragma unroll
        for (int mb = 0; mb < 4; ++mb) { aA[mb] = zf; aX[mb] = zf; tA[mb] = zf; tX[mb] = zf; }
#pragma unroll
        for (int kc = 0; kc < 2; ++kc) {
#pragma unroll
            for (int mb = 0; mb < 4; ++mb) {
                const int wo = (mb * 16 + s) * STRW + kc * 32 + q * 8;
                half8 wa = __builtin_bit_cast(half8, *(const uint4v*)&sWa[wo]);
                half8 wb = __builtin_bit_cast(half8, *(const uint4v*)&sWb[wo]);
                aA[mb] = __builtin_amdgcn_mfma_f32_16x16x32_f16(wa, H1a[kc], aA[mb], 0, 0, 0);
                aX[mb] = __builtin_amdgcn_mfma_f32_16x16x32_f16(wa, H1b[kc], aX[mb], 0, 0, 0);
                aX[mb] = __builtin_amdgcn_mfma_f32_16x16x32_f16(wb, H1a[kc], aX[mb], 0, 0, 0);
                tA[mb] = __builtin_amdgcn_mfma_f32_16x16x32_f16(wa, D1a[kc], tA[mb], 0, 0, 0);
                tX[mb] = __builtin_amdgcn_mfma_f32_16x16x32_f16(wa, D1b[kc], tX[mb], 0, 0, 0);
                tX[mb] = __builtin_amdgcn_mfma_f32_16x16x32_f16(wb, D1a[kc], tX[mb], 0, 0, 0);
            }
        }

        // ---- layer 3 + butterfly + outputs ----
        float rs = 0.f, js = 0.f;
#pragma unroll
        for (int mb = 0; mb < 4; ++mb) {
            f32x4 b2v = *(const f32x4*)&sb2[mb * 16 + q * 4];
            f32x4 w3v = *(const f32x4*)&sw3[mb * 16 + q * 4];
#pragma unroll
            for (int i = 0; i < 4; ++i) {
                float p  = fmaf(aX[mb][i], INVS, aA[mb][i]) + b2v[i];
                float dt = fmaf(tX[mb][i], INVS, tA[mb][i]);
                float h = fmaxf(p, 0.2f * p);
                float d = (p >= 0.f ? 1.f : 0.2f) * dt;
                rs = fmaf(w3v[i], h, rs);
                js = fmaf(w3v[i], d, js);
            }
        }
        rs += __shfl_xor(rs, 16, 64); rs += __shfl_xor(rs, 32, 64);
        js += __shfl_xor(js, 16, 64); js += __shfl_xor(js, 32, 64);
        if (lane < 16)
            out[(size_t)(bsmp * LENT + t) * 8 + l] = rs + b3v;
        ldAcc += __logf(fabsf(js));
    }

    if (lane < 16)
        out[(size_t)NSAMP * 8 + (size_t)bsmp * LENT + t] = ldAcc;
}

extern "C" void kernel_launch(void* const* d_in, const int* in_sizes, int n_in,
                              void* d_out, int out_size, void* d_ws, size_t ws_size,
                              hipStream_t stream) {
    (void)in_sizes; (void)n_in; (void)out_size; (void)d_ws; (void)ws_size;
    mlp_h2<<<dim3(LENT), 256, 0, stream>>>(
        (const float*)d_in[0], (const float*)d_in[1],
        (const float*)d_in[2], (const float*)d_in[3],
        (const float*)d_in[4], (const float*)d_in[5],
        (const float*)d_in[6], (const float*)d_in[7],
        (const float*)d_in[8], (const float*)d_in[9],
        (float*)d_out);
}